// Round 1
// baseline (599.145 us; speedup 1.0000x reference)
//
#include <hip/hip_runtime.h>
#include <hip/hip_bf16.h>
#include <stdint.h>

#define BATCH 2
#define HEADS 16
#define BH    32
#define SEQ   2048
#define DIM   128
#define ELEMS (BATCH*HEADS*SEQ*DIM)   // 8388608 per tensor

using f32x4  = __attribute__((ext_vector_type(4))) float;
using bf16x8 = __attribute__((ext_vector_type(8))) short;
using us4    = __attribute__((ext_vector_type(4))) unsigned short;

__device__ __forceinline__ unsigned short f2bf(float f) {
    union { float f; uint32_t u; } v; v.f = f;
    uint32_t u = v.u;
    uint32_t r = u + 0x7FFFu + ((u >> 16) & 1u);   // RNE
    return (unsigned short)(r >> 16);
}

// ---- prep: fp32 -> bf16 (row-major) ----
__global__ __launch_bounds__(256) void cvt_bf16(const float* __restrict__ in,
                                                unsigned short* __restrict__ out) {
    int i = (blockIdx.x * 256 + threadIdx.x) * 4;
    f32x4 v = *(const f32x4*)(in + i);
    us4 o;
    #pragma unroll
    for (int j = 0; j < 4; j++) o[j] = f2bf(v[j]);
    *(us4*)(out + i) = o;
}

// ---- prep: V fp32 [bh][n][d] -> VT bf16 [bh][d][n] ----
__global__ __launch_bounds__(256) void trans_v(const float* __restrict__ V,
                                               unsigned short* __restrict__ VT) {
    __shared__ unsigned short tile[32][36];
    int bh = blockIdx.z, n0 = blockIdx.y * 32, d0 = blockIdx.x * 32;
    int t = threadIdx.x;
    int row = t >> 3, c4 = (t & 7) * 4;
    f32x4 v = *(const f32x4*)(V + ((size_t)bh * SEQ + n0 + row) * DIM + d0 + c4);
    #pragma unroll
    for (int j = 0; j < 4; j++) tile[row][c4 + j] = f2bf(v[j]);
    __syncthreads();
    us4 o;
    #pragma unroll
    for (int j = 0; j < 4; j++) o[j] = tile[c4 + j][row];
    *(us4*)(VT + ((size_t)bh * DIM + d0 + row) * SEQ + n0 + c4) = o;
}

// ---- flash attention, swapped-QK^T, online softmax ----
// grid: (SEQ/64, BH), block: 256 (4 waves x 16 q-rows each), KVBLK=32
__global__ __launch_bounds__(256) void attn_fwd(const unsigned short* __restrict__ Qb,
                                                const unsigned short* __restrict__ Kb,
                                                const unsigned short* __restrict__ VTb,
                                                float* __restrict__ Out) {
    const int head = blockIdx.y;
    const int wid  = threadIdx.x >> 6;
    const int lane = threadIdx.x & 63;
    const int l15  = lane & 15;
    const int g    = lane >> 4;
    const int q0   = blockIdx.x * 64 + wid * 16;

    const unsigned short* Qh  = Qb  + (size_t)head * SEQ * DIM;
    const unsigned short* Kh  = Kb  + (size_t)head * SEQ * DIM;
    const unsigned short* VTh = VTb + (size_t)head * DIM * SEQ;

    // Q B-frags: lane holds Q[q0+l15][32c + 8g .. +7]
    bf16x8 qf[4];
    {
        const bf16x8* qrow = (const bf16x8*)(Qh + (size_t)(q0 + l15) * DIM);
        #pragma unroll
        for (int c = 0; c < 4; c++) qf[c] = qrow[4 * c + g];
    }

    f32x4 acc[8];
    #pragma unroll
    for (int m = 0; m < 8; m++) acc[m] = (f32x4){0.f, 0.f, 0.f, 0.f};
    float m_run = -INFINITY, l_run = 0.f;

    const float sc = 0.08838834764831845f * 1.4426950408889634f; // 1/sqrt(128) * log2(e)

    for (int kv0 = 0; kv0 < SEQ; kv0 += 32) {
        // S^T = K * Q^T  (two 16x16 blocks over kv)
        f32x4 s[2];
        #pragma unroll
        for (int t = 0; t < 2; t++) {
            s[t] = (f32x4){0.f, 0.f, 0.f, 0.f};
            const unsigned short* krow = Kh + (size_t)(kv0 + 16 * t + l15) * DIM + 8 * g;
            #pragma unroll
            for (int c = 0; c < 4; c++) {
                bf16x8 kf = *(const bf16x8*)(krow + 32 * c);
                s[t] = __builtin_amdgcn_mfma_f32_16x16x32_bf16(kf, qf[c], s[t], 0, 0, 0);
            }
        }
        // scale into exp2 domain; per-q max (8 in-lane + across 4 groups)
        float smax = -1e30f;
        #pragma unroll
        for (int t = 0; t < 2; t++)
            #pragma unroll
            for (int r = 0; r < 4; r++) {
                s[t][r] *= sc;
                smax = fmaxf(smax, s[t][r]);
            }
        smax = fmaxf(smax, __shfl_xor(smax, 16));
        smax = fmaxf(smax, __shfl_xor(smax, 32));

        float mnew = fmaxf(m_run, smax);
        float corr = __builtin_amdgcn_exp2f(m_run - mnew);   // 0 on first iter
        m_run = mnew;
        #pragma unroll
        for (int m = 0; m < 8; m++) acc[m] *= corr;

        float p[2][4];
        float psum = 0.f;
        #pragma unroll
        for (int t = 0; t < 2; t++)
            #pragma unroll
            for (int r = 0; r < 4; r++) {
                float e = __builtin_amdgcn_exp2f(s[t][r] - mnew);
                p[t][r] = e; psum += e;
            }
        psum += __shfl_xor(psum, 16);
        psum += __shfl_xor(psum, 32);
        l_run = l_run * corr + psum;

        // pack P to bf16 pairs; lane (group g) holds kv = 16t + 4g + r
        uint32_t pk0[2], pk1[2];
        #pragma unroll
        for (int j = 0; j < 2; j++) {
            pk0[j] = (uint32_t)f2bf(p[0][2 * j]) | ((uint32_t)f2bf(p[0][2 * j + 1]) << 16);
            pk1[j] = (uint32_t)f2bf(p[1][2 * j]) | ((uint32_t)f2bf(p[1][2 * j + 1]) << 16);
        }
        // build PV B-frag: lane needs P^T[8g+b][q=l15], b=0..7
        union { uint32_t w[4]; bf16x8 v; } pf;
        const int baseSrc = l15 + 16 * (2 * (g & 1));
        #pragma unroll
        for (int r = 0; r < 4; r++) {
            int srcLane = baseSrc + 16 * (r >> 1);
            uint32_t a0 = (uint32_t)__shfl((int)pk0[r & 1], srcLane, 64);
            uint32_t a1 = (uint32_t)__shfl((int)pk1[r & 1], srcLane, 64);
            pf.w[r] = (g >= 2) ? a1 : a0;
        }
        // O^T += V^T * P^T : A-frag = VT[16m+l15][kv0+8g..+7] contiguous
        #pragma unroll
        for (int m = 0; m < 8; m++) {
            bf16x8 vf = *(const bf16x8*)(VTh + (size_t)(16 * m + l15) * SEQ + kv0 + 8 * g);
            acc[m] = __builtin_amdgcn_mfma_f32_16x16x32_bf16(vf, pf.v, acc[m], 0, 0, 0);
        }
    }

    // epilogue: normalize, transpose O^T -> O via LDS, coalesced fp32 stores
    const float inv = 1.0f / l_run;
    __shared__ float obuf[4][16][132];
    #pragma unroll
    for (int m = 0; m < 8; m++) {
        f32x4 o = acc[m] * inv;
        *(f32x4*)&obuf[wid][l15][16 * m + 4 * g] = o;
    }
    __syncthreads();
    {
        int row = lane >> 2, cg = (lane & 3) * 32;
        const float* src = &obuf[wid][row][cg];
        float* dst = Out + (size_t)head * SEQ * DIM + (size_t)(q0 + row) * DIM + cg;
        #pragma unroll
        for (int i = 0; i < 8; i++)
            *(f32x4*)(dst + 4 * i) = *(const f32x4*)(src + 4 * i);
    }
}

extern "C" void kernel_launch(void* const* d_in, const int* in_sizes, int n_in,
                              void* d_out, int out_size, void* d_ws, size_t ws_size,
                              hipStream_t stream) {
    (void)in_sizes; (void)n_in; (void)out_size;
    const float* q = (const float*)d_in[0];
    const float* k = (const float*)d_in[1];
    const float* v = (const float*)d_in[2];
    float* out = (float*)d_out;

    const size_t needed = (size_t)ELEMS * 2 * 3;
    if (ws_size < needed) return;  // insufficient scratch; will show as incorrect

    unsigned short* qb = (unsigned short*)d_ws;
    unsigned short* kb = qb + ELEMS;
    unsigned short* vt = kb + ELEMS;

    cvt_bf16<<<ELEMS / 4 / 256, 256, 0, stream>>>(q, qb);
    cvt_bf16<<<ELEMS / 4 / 256, 256, 0, stream>>>(k, kb);
    trans_v<<<dim3(DIM / 32, SEQ / 32, BH), 256, 0, stream>>>(v, vt);
    attn_fwd<<<dim3(SEQ / 64, BH), 256, 0, stream>>>(qb, kb, vt, out);
}

// Round 2
// 225.465 us; speedup vs baseline: 2.6574x; 2.6574x over previous
//
#include <hip/hip_runtime.h>
#include <hip/hip_bf16.h>
#include <stdint.h>

#define BATCH 2
#define HEADS 16
#define BH    32
#define SEQ   2048
#define DIM   128
#define ELEMS (BATCH*HEADS*SEQ*DIM)   // 8388608 per tensor

#define KVB   64
#define NT    (SEQ/KVB)               // 32 tiles

using f32x4  = __attribute__((ext_vector_type(4))) float;
using f32x16 = __attribute__((ext_vector_type(16))) float;
using bf16x8 = __attribute__((ext_vector_type(8))) short;
using us4    = __attribute__((ext_vector_type(4))) unsigned short;

__device__ __forceinline__ unsigned short f2bf(float f) {
    union { float f; uint32_t u; } v; v.f = f;
    uint32_t u = v.u;
    uint32_t r = u + 0x7FFFu + ((u >> 16) & 1u);   // RNE
    return (unsigned short)(r >> 16);
}

__device__ __forceinline__ uint32_t packbf2(float lo, float hi) {
    __hip_bfloat162 h2 = __float22bfloat162_rn(make_float2(lo, hi));
    union { __hip_bfloat162 h; uint32_t u; } c; c.h = h2;
    return c.u;   // low16 = lo, high16 = hi
}

// ---- prep: fp32 -> bf16 (row-major) ----
__global__ __launch_bounds__(256) void cvt_bf16(const float* __restrict__ in,
                                                unsigned short* __restrict__ out) {
    int i = (blockIdx.x * 256 + threadIdx.x) * 4;
    f32x4 v = *(const f32x4*)(in + i);
    us4 o;
    #pragma unroll
    for (int j = 0; j < 4; j++) o[j] = f2bf(v[j]);
    *(us4*)(out + i) = o;
}

// ---- prep: V fp32 [bh][n][d] -> VT bf16 [bh][d][n] ----
__global__ __launch_bounds__(256) void trans_v(const float* __restrict__ V,
                                               unsigned short* __restrict__ VT) {
    __shared__ unsigned short tile[32][36];
    int bh = blockIdx.z, n0 = blockIdx.y * 32, d0 = blockIdx.x * 32;
    int t = threadIdx.x;
    int row = t >> 3, c4 = (t & 7) * 4;
    f32x4 v = *(const f32x4*)(V + ((size_t)bh * SEQ + n0 + row) * DIM + d0 + c4);
    #pragma unroll
    for (int j = 0; j < 4; j++) tile[row][c4 + j] = f2bf(v[j]);
    __syncthreads();
    us4 o;
    #pragma unroll
    for (int j = 0; j < 4; j++) o[j] = tile[c4 + j][row];
    *(us4*)(VT + ((size_t)bh * DIM + d0 + row) * SEQ + n0 + c4) = o;
}

// ---- flash attention: 4 waves x QBLK=32, KVBLK=64, 32x32x16 MFMA ----
// LDS: K dbuf [2][64 rows][256B, 16-slot swizzle], VT dbuf [2][64 rowpairs][256B, pair-swizzle]
__global__ __launch_bounds__(256, 2) void attn_fwd(const unsigned short* __restrict__ Qb,
                                                   const unsigned short* __restrict__ Kb,
                                                   const unsigned short* __restrict__ VTb,
                                                   float* __restrict__ Out) {
    __shared__ __attribute__((aligned(16))) char smem[65536];

    const int head = blockIdx.y;
    const int wid  = threadIdx.x >> 6;
    const int lane = threadIdx.x & 63;
    const int l31  = lane & 31;
    const int hL   = lane >> 5;
    const int q0   = blockIdx.x * 128 + wid * 32;

    const unsigned short* Qh = Qb + (size_t)head * SEQ * DIM;
    const char* KhB  = (const char*)(Kb  + (size_t)head * SEQ * DIM);
    const char* VThB = (const char*)(VTb + (size_t)head * DIM * SEQ);

    // Q B-frags: lane holds Q[q0+l31][16u + 8hL .. +7], u=0..7
    bf16x8 qf[8];
    {
        const char* qrow = (const char*)(Qh + (size_t)(q0 + l31) * DIM) + 16 * hL;
        #pragma unroll
        for (int u = 0; u < 8; ++u) qf[u] = *(const bf16x8*)(qrow + 32 * u);
    }

    f32x16 acc[4];
    #pragma unroll
    for (int m = 0; m < 4; ++m) acc[m] = (f32x16)(0.f);
    float m_run = -INFINITY, l_run = 0.f;
    const float sc = 0.08838834764831845f * 1.4426950408889634f; // 1/sqrt(128)*log2(e)

    const int swzK = (l31 & 15) << 4;          // K read swizzle
    const int swzV = ((l31 >> 1) & 7) << 4;    // VT read swizzle (row-pair)

    // stage one KV tile (K: 16KB + VT: 16KB), 8 global_load_lds x16B per wave
    auto STAGE = [&](int buf, int kv0) {
        #pragma unroll
        for (int i = 0; i < 4; ++i) {
            int seg = wid * 4 + i;
            int r   = seg * 4 + (lane >> 4);
            int cb  = ((lane & 15) << 4) ^ ((r & 15) << 4);
            const char* g = KhB + (((size_t)(kv0 + r)) << 8) + cb;
            __builtin_amdgcn_global_load_lds(
                (const __attribute__((address_space(1))) void*)g,
                (__attribute__((address_space(3))) void*)(smem + buf * 16384 + seg * 1024),
                16, 0, 0);
        }
        #pragma unroll
        for (int i = 0; i < 4; ++i) {
            int seg = wid * 4 + i;
            int rp  = seg * 4 + (lane >> 4);          // row-pair 0..63
            int q8  = (lane & 15) << 4;
            int pre = q8 ^ ((rp & 7) << 4);
            int r   = 2 * rp + (pre >> 7);            // VT d-row 0..127
            int cb  = pre & 127;
            const char* g = VThB + (size_t)r * (SEQ * 2) + ((size_t)kv0 << 1) + cb;
            __builtin_amdgcn_global_load_lds(
                (const __attribute__((address_space(1))) void*)g,
                (__attribute__((address_space(3))) void*)(smem + 32768 + buf * 16384 + seg * 1024),
                16, 0, 0);
        }
    };

    STAGE(0, 0);

    for (int t = 0; t < NT; ++t) {
        const int cur = t & 1;
        if (t + 1 < NT) {
            STAGE(cur ^ 1, (t + 1) * KVB);
            asm volatile("s_waitcnt vmcnt(8)" ::: "memory");  // cur tile staged; next 8 in flight
        } else {
            asm volatile("s_waitcnt vmcnt(0)" ::: "memory");
        }
        __builtin_amdgcn_s_barrier();
        asm volatile("" ::: "memory");

        const char* kb = smem + cur * 16384;
        const char* vb = smem + 32768 + cur * 16384;

        // ---- QK^T: S^T[kv][q], two 32x32 subtiles over kv ----
        f32x16 s0 = (f32x16)(0.f), s1 = (f32x16)(0.f);
        {
            const char* krow0 = kb + (size_t)l31 * 256;
            const char* krow1 = kb + (size_t)(32 + l31) * 256;
            #pragma unroll
            for (int u = 0; u < 8; ++u) {
                int cb = (32 * u + 16 * hL) ^ swzK;
                bf16x8 k0 = *(const bf16x8*)(krow0 + cb);
                bf16x8 k1 = *(const bf16x8*)(krow1 + cb);
                s0 = __builtin_amdgcn_mfma_f32_32x32x16_bf16(k0, qf[u], s0, 0, 0, 0);
                s1 = __builtin_amdgcn_mfma_f32_32x32x16_bf16(k1, qf[u], s1, 0, 0, 0);
            }
        }

        // ---- online softmax (per q-column; partner lane holds other 32 kv) ----
        float smax = -1e30f;
        #pragma unroll
        for (int r = 0; r < 16; ++r) {
            s0[r] *= sc; s1[r] *= sc;
            smax = fmaxf(smax, fmaxf(s0[r], s1[r]));
        }
        smax = fmaxf(smax, __shfl_xor(smax, 32));

        if (!__all(smax - m_run <= 8.f)) {          // defer-max (T13)
            float mnew = fmaxf(m_run, smax);
            float corr = __builtin_amdgcn_exp2f(m_run - mnew);
            #pragma unroll
            for (int m = 0; m < 4; ++m) acc[m] *= corr;
            l_run *= corr;
            m_run = mnew;
        }

        float psum = 0.f;
        #pragma unroll
        for (int r = 0; r < 16; ++r) {
            s0[r] = __builtin_amdgcn_exp2f(s0[r] - m_run);
            s1[r] = __builtin_amdgcn_exp2f(s1[r] - m_run);
            psum += s0[r] + s1[r];
        }
        psum += __shfl_xor(psum, 32);
        l_run += psum;

        // ---- pack P to bf16 dword pairs ----
        uint32_t w0[8], w1[8];
        #pragma unroll
        for (int k2 = 0; k2 < 8; ++k2) {
            w0[k2] = packbf2(s0[2 * k2], s0[2 * k2 + 1]);
            w1[k2] = packbf2(s1[2 * k2], s1[2 * k2 + 1]);
        }

        // ---- PV: O^T[d][q] += V^T * P^T ----
        #pragma unroll
        for (int tt = 0; tt < 2; ++tt) {
            #pragma unroll
            for (int ssi = 0; ssi < 2; ++ssi) {
                uint32_t A0 = tt ? w1[4 * ssi]     : w0[4 * ssi];
                uint32_t A1 = tt ? w1[4 * ssi + 1] : w0[4 * ssi + 1];
                uint32_t C0 = tt ? w1[4 * ssi + 2] : w0[4 * ssi + 2];
                uint32_t C1 = tt ? w1[4 * ssi + 3] : w0[4 * ssi + 3];
                uint32_t o0 = hL ? A0 : C0;
                uint32_t o1 = hL ? A1 : C1;
                uint32_t e0 = (uint32_t)__shfl_xor((int)o0, 32);
                uint32_t e1 = (uint32_t)__shfl_xor((int)o1, 32);
                union { uint32_t u[4]; bf16x8 v; } B;
                B.u[0] = hL ? e0 : A0;
                B.u[1] = hL ? e1 : A1;
                B.u[2] = hL ? C0 : e0;
                B.u[3] = hL ? C1 : e1;
                const int cbv = (32 * (2 * tt + ssi) + 16 * hL) + ((l31 & 1) << 7);
                #pragma unroll
                for (int m = 0; m < 4; ++m) {
                    int rp = 16 * m + (l31 >> 1);
                    bf16x8 vf = *(const bf16x8*)(vb + (size_t)rp * 256 + (cbv ^ swzV));
                    acc[m] = __builtin_amdgcn_mfma_f32_32x32x16_bf16(vf, B.v, acc[m], 0, 0, 0);
                }
            }
        }

        asm volatile("" ::: "memory");
        __builtin_amdgcn_s_barrier();   // all waves done reading cur -> safe to overwrite
    }

    // ---- epilogue: O^T regs -> swizzled LDS -> coalesced fp32 stores ----
    __syncthreads();
    const float inv = 1.0f / l_run;
    float* ob = (float*)(smem + wid * 16384);   // 32 q-rows x 128 f32, XOR-swizzled
    #pragma unroll
    for (int m = 0; m < 4; ++m) {
        #pragma unroll
        for (int r = 0; r < 16; ++r) {
            int d = 32 * m + (r & 3) + 8 * (r >> 2) + 4 * hL;
            ob[l31 * 128 + (d ^ ((l31 & 7) << 2))] = acc[m][r] * inv;
        }
    }
    __syncthreads();
    {
        float* outp = Out + ((size_t)head * SEQ + q0) * DIM;
        #pragma unroll
        for (int i = 0; i < 16; ++i) {
            int row = 2 * i + hL;
            f32x4 v = *(const f32x4*)(ob + row * 128 + ((4 * l31) ^ ((row & 7) << 2)));
            *(f32x4*)(outp + (size_t)row * DIM + 4 * l31) = v;
        }
    }
}

extern "C" void kernel_launch(void* const* d_in, const int* in_sizes, int n_in,
                              void* d_out, int out_size, void* d_ws, size_t ws_size,
                              hipStream_t stream) {
    (void)in_sizes; (void)n_in; (void)out_size;
    const float* q = (const float*)d_in[0];
    const float* k = (const float*)d_in[1];
    const float* v = (const float*)d_in[2];
    float* out = (float*)d_out;

    const size_t needed = (size_t)ELEMS * 2 * 3;
    if (ws_size < needed) return;

    unsigned short* qb = (unsigned short*)d_ws;
    unsigned short* kb = qb + ELEMS;
    unsigned short* vt = kb + ELEMS;

    cvt_bf16<<<ELEMS / 4 / 256, 256, 0, stream>>>(q, qb);
    cvt_bf16<<<ELEMS / 4 / 256, 256, 0, stream>>>(k, kb);
    trans_v<<<dim3(DIM / 32, SEQ / 32, BH), 256, 0, stream>>>(v, vt);
    attn_fwd<<<dim3(SEQ / 128, BH), 256, 0, stream>>>(qb, kb, vt, out);
}

// Round 3
// 220.032 us; speedup vs baseline: 2.7230x; 1.0247x over previous
//
#include <hip/hip_runtime.h>
#include <hip/hip_bf16.h>
#include <stdint.h>

#define BATCH 2
#define HEADS 16
#define BH    32
#define SEQ   2048
#define DIM   128
#define ELEMS (BATCH*HEADS*SEQ*DIM)   // 8388608 per tensor

#define KVB   64
#define NT    (SEQ/KVB)               // 32 tiles

using f32x4  = __attribute__((ext_vector_type(4))) float;
using f32x16 = __attribute__((ext_vector_type(16))) float;
using bf16x8 = __attribute__((ext_vector_type(8))) short;
using us4    = __attribute__((ext_vector_type(4))) unsigned short;

__device__ __forceinline__ unsigned short f2bf(float f) {
    union { float f; uint32_t u; } v; v.f = f;
    uint32_t u = v.u;
    uint32_t r = u + 0x7FFFu + ((u >> 16) & 1u);   // RNE
    return (unsigned short)(r >> 16);
}

__device__ __forceinline__ uint32_t packbf2(float lo, float hi) {
    __hip_bfloat162 h2 = __float22bfloat162_rn(make_float2(lo, hi));
    union { __hip_bfloat162 h; uint32_t u; } c; c.h = h2;
    return c.u;   // low16 = lo, high16 = hi
}

// ---- fused prep: blocks [0,2048): K fp32->bf16; [2048,4096): V fp32 -> VT bf16 ----
__global__ __launch_bounds__(256) void prep(const float* __restrict__ K,
                                            const float* __restrict__ V,
                                            unsigned short* __restrict__ kb,
                                            unsigned short* __restrict__ vt) {
    const int b = blockIdx.x, t = threadIdx.x;
    if (b < 2048) {
        size_t base = (size_t)b * 4096 + t * 4;
        #pragma unroll
        for (int j = 0; j < 4; ++j) {
            f32x4 v = *(const f32x4*)(K + base + j * 1024);
            us4 o;
            #pragma unroll
            for (int jj = 0; jj < 4; ++jj) o[jj] = f2bf(v[jj]);
            *(us4*)(kb + base + j * 1024) = o;
        }
    } else {
        __shared__ unsigned short tile[64][66];
        const int b2 = b - 2048;
        const int bh = b2 >> 6, rem = b2 & 63;
        const int n0 = (rem >> 1) * 64, d0 = (rem & 1) * 64;
        const int rr = t >> 4, cc = t & 15;
        #pragma unroll
        for (int j = 0; j < 4; ++j) {
            int row = rr + 16 * j;
            f32x4 v = *(const f32x4*)(V + ((size_t)bh * SEQ + n0 + row) * DIM + d0 + cc * 4);
            #pragma unroll
            for (int jj = 0; jj < 4; ++jj) tile[row][cc * 4 + jj] = f2bf(v[jj]);
        }
        __syncthreads();
        #pragma unroll
        for (int j = 0; j < 4; ++j) {
            int drow = rr + 16 * j;
            us4 o;
            #pragma unroll
            for (int jj = 0; jj < 4; ++jj) o[jj] = tile[cc * 4 + jj][drow];
            *(us4*)(vt + ((size_t)bh * DIM + d0 + drow) * SEQ + n0 + cc * 4) = o;
        }
    }
}

// ---- flash attention: 4 waves x QBLK=32, KVBLK=64, 32x32x16 MFMA ----
__global__ __launch_bounds__(256, 2) void attn_fwd(const float* __restrict__ Qf,
                                                   const unsigned short* __restrict__ Kb,
                                                   const unsigned short* __restrict__ VTb,
                                                   float* __restrict__ Out) {
    __shared__ __attribute__((aligned(16))) char smem[65536];

    const int head = blockIdx.y;
    const int wid  = threadIdx.x >> 6;
    const int lane = threadIdx.x & 63;
    const int l31  = lane & 31;
    const int hL   = lane >> 5;
    const int q0   = blockIdx.x * 128 + wid * 32;

    const char* KhB  = (const char*)(Kb  + (size_t)head * SEQ * DIM);
    const char* VThB = (const char*)(VTb + (size_t)head * DIM * SEQ);

    // Q: fp32 direct load, convert to bf16 frags pre-scaled into exp2 domain
    const float scl = 0.08838834764831845f * 1.4426950408889634f; // 1/sqrt(128)*log2(e)
    bf16x8 qf[8];
    {
        const float* qrow = Qf + ((size_t)head * SEQ + q0 + l31) * DIM + 8 * hL;
        #pragma unroll
        for (int u = 0; u < 8; ++u) {
            f32x4 a = *(const f32x4*)(qrow + 16 * u);
            f32x4 b = *(const f32x4*)(qrow + 16 * u + 4);
            union { uint32_t w[4]; bf16x8 v; } P;
            P.w[0] = packbf2(a[0] * scl, a[1] * scl);
            P.w[1] = packbf2(a[2] * scl, a[3] * scl);
            P.w[2] = packbf2(b[0] * scl, b[1] * scl);
            P.w[3] = packbf2(b[2] * scl, b[3] * scl);
            qf[u] = P.v;
        }
    }

    f32x16 acc[4];
    #pragma unroll
    for (int m = 0; m < 4; ++m) acc[m] = (f32x16)(0.f);
    float m_run = -INFINITY, l_run = 0.f;

    const int swzK = (l31 & 15) << 4;          // K read swizzle
    const int swzV = ((l31 >> 1) & 7) << 4;    // VT read swizzle (row-pair)

    auto STAGE = [&](int buf, int kv0) {
        #pragma unroll
        for (int i = 0; i < 4; ++i) {
            int seg = wid * 4 + i;
            int r   = seg * 4 + (lane >> 4);
            int cb  = ((lane & 15) << 4) ^ ((r & 15) << 4);
            const char* g = KhB + (((size_t)(kv0 + r)) << 8) + cb;
            __builtin_amdgcn_global_load_lds(
                (const __attribute__((address_space(1))) void*)g,
                (__attribute__((address_space(3))) void*)(smem + buf * 16384 + seg * 1024),
                16, 0, 0);
        }
        #pragma unroll
        for (int i = 0; i < 4; ++i) {
            int seg = wid * 4 + i;
            int rp  = seg * 4 + (lane >> 4);          // row-pair 0..63
            int q8  = (lane & 15) << 4;
            int pre = q8 ^ ((rp & 7) << 4);
            int r   = 2 * rp + (pre >> 7);            // VT d-row 0..127
            int cb  = pre & 127;
            const char* g = VThB + (size_t)r * (SEQ * 2) + ((size_t)kv0 << 1) + cb;
            __builtin_amdgcn_global_load_lds(
                (const __attribute__((address_space(1))) void*)g,
                (__attribute__((address_space(3))) void*)(smem + 32768 + buf * 16384 + seg * 1024),
                16, 0, 0);
        }
    };

    STAGE(0, 0);

    for (int t = 0; t < NT; ++t) {
        const int cur = t & 1;
        if (t + 1 < NT) {
            STAGE(cur ^ 1, (t + 1) * KVB);
            asm volatile("s_waitcnt vmcnt(8)" ::: "memory");
        } else {
            asm volatile("s_waitcnt vmcnt(0)" ::: "memory");
        }
        __builtin_amdgcn_s_barrier();
        asm volatile("" ::: "memory");

        const char* kb = smem + cur * 16384;
        const char* vb = smem + 32768 + cur * 16384;

        // ---- QK^T: S^T[kv][q] ----
        f32x16 s0 = (f32x16)(0.f), s1 = (f32x16)(0.f);
        __builtin_amdgcn_s_setprio(1);
        {
            const char* krow0 = kb + (size_t)l31 * 256;
            const char* krow1 = kb + (size_t)(32 + l31) * 256;
            #pragma unroll
            for (int u = 0; u < 8; ++u) {
                int cb = (32 * u + 16 * hL) ^ swzK;
                bf16x8 k0 = *(const bf16x8*)(krow0 + cb);
                bf16x8 k1 = *(const bf16x8*)(krow1 + cb);
                s0 = __builtin_amdgcn_mfma_f32_32x32x16_bf16(k0, qf[u], s0, 0, 0, 0);
                s1 = __builtin_amdgcn_mfma_f32_32x32x16_bf16(k1, qf[u], s1, 0, 0, 0);
            }
        }
        __builtin_amdgcn_s_setprio(0);

        // ---- hoist V fragment loads; LDS latency hides under softmax ----
        bf16x8 vf[2][2][4];
        #pragma unroll
        for (int tt = 0; tt < 2; ++tt)
            #pragma unroll
            for (int ssi = 0; ssi < 2; ++ssi) {
                const int cbv = (32 * (2 * tt + ssi) + 16 * hL) + ((l31 & 1) << 7);
                #pragma unroll
                for (int m = 0; m < 4; ++m) {
                    int rp = 16 * m + (l31 >> 1);
                    vf[tt][ssi][m] = *(const bf16x8*)(vb + (size_t)rp * 256 + (cbv ^ swzV));
                }
            }

        // ---- online softmax (scale already folded into Q) ----
        float smax = -1e30f;
        #pragma unroll
        for (int r = 0; r < 16; ++r)
            smax = fmaxf(smax, fmaxf(s0[r], s1[r]));
        smax = fmaxf(smax, __shfl_xor(smax, 16) * 0.f + __shfl_xor(smax, 32)); // pair reduce
        // (the *0.f term is dead; keep simple:)
        if (!__all(smax - m_run <= 8.f)) {          // defer-max (T13)
            float mnew = fmaxf(m_run, smax);
            float corr = __builtin_amdgcn_exp2f(m_run - mnew);
            #pragma unroll
            for (int m = 0; m < 4; ++m) acc[m] *= corr;
            l_run *= corr;
            m_run = mnew;
        }

        float psum = 0.f;
        #pragma unroll
        for (int r = 0; r < 16; ++r) {
            s0[r] = __builtin_amdgcn_exp2f(s0[r] - m_run);
            s1[r] = __builtin_amdgcn_exp2f(s1[r] - m_run);
            psum += s0[r] + s1[r];
        }
        l_run += psum;   // lane-local; pair-reduced once at the end

        // ---- pack P to bf16 dword pairs ----
        uint32_t w0[8], w1[8];
        #pragma unroll
        for (int k2 = 0; k2 < 8; ++k2) {
            w0[k2] = packbf2(s0[2 * k2], s0[2 * k2 + 1]);
            w1[k2] = packbf2(s1[2 * k2], s1[2 * k2 + 1]);
        }

        // ---- PV: O^T[d][q] += V^T * P^T ----
        __builtin_amdgcn_s_setprio(1);
        #pragma unroll
        for (int tt = 0; tt < 2; ++tt) {
            #pragma unroll
            for (int ssi = 0; ssi < 2; ++ssi) {
                uint32_t A0 = tt ? w1[4 * ssi]     : w0[4 * ssi];
                uint32_t A1 = tt ? w1[4 * ssi + 1] : w0[4 * ssi + 1];
                uint32_t C0 = tt ? w1[4 * ssi + 2] : w0[4 * ssi + 2];
                uint32_t C1 = tt ? w1[4 * ssi + 3] : w0[4 * ssi + 3];
                uint32_t o0 = hL ? A0 : C0;
                uint32_t o1 = hL ? A1 : C1;
                uint32_t e0 = (uint32_t)__shfl_xor((int)o0, 32);
                uint32_t e1 = (uint32_t)__shfl_xor((int)o1, 32);
                union { uint32_t u[4]; bf16x8 v; } Bf;
                Bf.u[0] = hL ? e0 : A0;
                Bf.u[1] = hL ? e1 : A1;
                Bf.u[2] = hL ? C0 : e0;
                Bf.u[3] = hL ? C1 : e1;
                #pragma unroll
                for (int m = 0; m < 4; ++m)
                    acc[m] = __builtin_amdgcn_mfma_f32_32x32x16_bf16(vf[tt][ssi][m], Bf.v, acc[m], 0, 0, 0);
            }
        }
        __builtin_amdgcn_s_setprio(0);

        asm volatile("" ::: "memory");
        __builtin_amdgcn_s_barrier();
    }

    // ---- epilogue ----
    __syncthreads();
    const float l_tot = l_run + __shfl_xor(l_run, 32);
    const float inv = 1.0f / l_tot;
    float* ob = (float*)(smem + wid * 16384);
    #pragma unroll
    for (int m = 0; m < 4; ++m) {
        #pragma unroll
        for (int r = 0; r < 16; ++r) {
            int d = 32 * m + (r & 3) + 8 * (r >> 2) + 4 * hL;
            ob[l31 * 128 + (d ^ ((l31 & 7) << 2))] = acc[m][r] * inv;
        }
    }
    __syncthreads();
    {
        float* outp = Out + ((size_t)head * SEQ + q0) * DIM;
        #pragma unroll
        for (int i = 0; i < 16; ++i) {
            int row = 2 * i + hL;
            f32x4 v = *(const f32x4*)(ob + row * 128 + ((4 * l31) ^ ((row & 7) << 2)));
            *(f32x4*)(outp + (size_t)row * DIM + 4 * l31) = v;
        }
    }
}

extern "C" void kernel_launch(void* const* d_in, const int* in_sizes, int n_in,
                              void* d_out, int out_size, void* d_ws, size_t ws_size,
                              hipStream_t stream) {
    (void)in_sizes; (void)n_in; (void)out_size;
    const float* q = (const float*)d_in[0];
    const float* k = (const float*)d_in[1];
    const float* v = (const float*)d_in[2];
    float* out = (float*)d_out;

    const size_t needed = (size_t)ELEMS * 2 * 2;
    if (ws_size < needed) return;

    unsigned short* kb = (unsigned short*)d_ws;
    unsigned short* vt = kb + ELEMS;

    prep<<<4096, 256, 0, stream>>>(k, v, kb, vt);
    attn_fwd<<<dim3(SEQ / 128, BH), 256, 0, stream>>>(q, kb, vt, out);
}